// Round 8
// baseline (553.363 us; speedup 1.0000x reference)
//
#include <hip/hip_runtime.h>

typedef __bf16 bf16x8 __attribute__((ext_vector_type(8)));
typedef unsigned short u16x8v __attribute__((ext_vector_type(8)));
typedef unsigned short u16x4v __attribute__((ext_vector_type(4)));
typedef float f32x4 __attribute__((ext_vector_type(4)));

constexpr int SEQ = 2048;
constexpr int DIM = 1024;
constexpr int BATCH = 4;
constexpr size_t NBS = (size_t)BATCH * SEQ * DIM;  // 8388608

static __device__ __forceinline__ unsigned short f2bf(float f) {
    unsigned int u = __builtin_bit_cast(unsigned int, f);
    u += 0x7FFFu + ((u >> 16) & 1u);  // RNE
    return (unsigned short)(u >> 16);
}
static __device__ __forceinline__ float bf2f(unsigned short h) {
    return __builtin_bit_cast(float, (unsigned int)h << 16);
}
static __device__ __forceinline__ bf16x8 ldsld(const unsigned short* p) {
    return __builtin_bit_cast(bf16x8, *(const u16x8v*)p);
}

// ---------------------------------------------------------------------------
// fp32 -> bf16 hi + bf16 lo (lo = rne(x - hi)); 4 elems/thread.
// ---------------------------------------------------------------------------
__global__ __launch_bounds__(256) void split_f32(
    const float* __restrict__ in, unsigned short* __restrict__ hi,
    unsigned short* __restrict__ lo, int n4)
{
    int i = blockIdx.x * 256 + threadIdx.x;
    if (i >= n4) return;
    float4 f = ((const float4*)in)[i];
    u16x4v h, l;
    h.x = f2bf(f.x); l.x = f2bf(f.x - bf2f(h.x));
    h.y = f2bf(f.y); l.y = f2bf(f.y - bf2f(h.y));
    h.z = f2bf(f.z); l.z = f2bf(f.z - bf2f(h.z));
    h.w = f2bf(f.w); l.w = f2bf(f.w - bf2f(h.w));
    ((u16x4v*)hi)[i] = h;
    ((u16x4v*)lo)[i] = l;
}

// ---------------------------------------------------------------------------
// QKV GEMM (NT, W [out,in]). 128x128 tile, 4 waves x 64x64 (4x4 MFMA).
// z<2 (Q,K): split-3 MFMA (hh+hl+lh) -> fp32-faithful, stored as bf16 hi.
// z=2 (V): single hh term (V is bf16 downstream anyway); stored transposed
// Vt[b][d][s].
// ---------------------------------------------------------------------------
__global__ __launch_bounds__(256) void qkv_gemm3(
    const unsigned short* __restrict__ Xh, const unsigned short* __restrict__ Xl,
    const unsigned short* __restrict__ Wh, const unsigned short* __restrict__ Wl,
    unsigned short* __restrict__ Qh, unsigned short* __restrict__ Kh,
    unsigned short* __restrict__ Vt)
{
    __shared__ unsigned short Ah[128 * 40], Al[128 * 40];
    __shared__ unsigned short Bh[128 * 40], Bl[128 * 40];
    const int m0 = blockIdx.x * 128, n0 = blockIdx.y * 128, z = blockIdx.z;
    const bool split3 = (z < 2);
    const unsigned short* Wzh = Wh + (size_t)z * DIM * DIM;
    const unsigned short* Wzl = Wl + (size_t)z * DIM * DIM;
    const int tid = threadIdx.x;
    const int w = tid >> 6, lane = tid & 63, q = lane >> 4, c = lane & 15;
    const int wrow = (w >> 1) * 64, wcol = (w & 1) * 64;

    f32x4 acc[4][4];
#pragma unroll
    for (int a = 0; a < 4; ++a)
#pragma unroll
        for (int b = 0; b < 4; ++b) acc[a][b] = (f32x4){0.f, 0.f, 0.f, 0.f};

    const int srow = tid >> 1, sh = (tid & 1) * 16;
    for (int k0 = 0; k0 < DIM; k0 += 32) {
        __syncthreads();
        {
            const size_t ga = (size_t)(m0 + srow) * DIM + k0 + sh;
            const size_t gb = (size_t)(n0 + srow) * DIM + k0 + sh;
            unsigned short* sa  = Ah + srow * 40 + sh;
            unsigned short* sb  = Bh + srow * 40 + sh;
            *(u16x8v*)sa        = *(const u16x8v*)(Xh + ga);
            *(u16x8v*)(sa + 8)  = *(const u16x8v*)(Xh + ga + 8);
            *(u16x8v*)sb        = *(const u16x8v*)(Wzh + gb);
            *(u16x8v*)(sb + 8)  = *(const u16x8v*)(Wzh + gb + 8);
            if (split3) {
                unsigned short* sal = Al + srow * 40 + sh;
                unsigned short* sbl = Bl + srow * 40 + sh;
                *(u16x8v*)sal       = *(const u16x8v*)(Xl + ga);
                *(u16x8v*)(sal + 8) = *(const u16x8v*)(Xl + ga + 8);
                *(u16x8v*)sbl       = *(const u16x8v*)(Wzl + gb);
                *(u16x8v*)(sbl + 8) = *(const u16x8v*)(Wzl + gb + 8);
            }
        }
        __syncthreads();
        bf16x8 ah[4], bh[4];
#pragma unroll
        for (int mi = 0; mi < 4; ++mi)
            ah[mi] = ldsld(Ah + (wrow + mi * 16 + c) * 40 + q * 8);
#pragma unroll
        for (int ni = 0; ni < 4; ++ni)
            bh[ni] = ldsld(Bh + (wcol + ni * 16 + c) * 40 + q * 8);
        if (split3) {
            bf16x8 al[4], bl[4];
#pragma unroll
            for (int mi = 0; mi < 4; ++mi)
                al[mi] = ldsld(Al + (wrow + mi * 16 + c) * 40 + q * 8);
#pragma unroll
            for (int ni = 0; ni < 4; ++ni)
                bl[ni] = ldsld(Bl + (wcol + ni * 16 + c) * 40 + q * 8);
#pragma unroll
            for (int mi = 0; mi < 4; ++mi)
#pragma unroll
                for (int ni = 0; ni < 4; ++ni) {
                    acc[mi][ni] = __builtin_amdgcn_mfma_f32_16x16x32_bf16(al[mi], bh[ni], acc[mi][ni], 0, 0, 0);
                    acc[mi][ni] = __builtin_amdgcn_mfma_f32_16x16x32_bf16(ah[mi], bl[ni], acc[mi][ni], 0, 0, 0);
                    acc[mi][ni] = __builtin_amdgcn_mfma_f32_16x16x32_bf16(ah[mi], bh[ni], acc[mi][ni], 0, 0, 0);
                }
        } else {
#pragma unroll
            for (int mi = 0; mi < 4; ++mi)
#pragma unroll
                for (int ni = 0; ni < 4; ++ni)
                    acc[mi][ni] = __builtin_amdgcn_mfma_f32_16x16x32_bf16(ah[mi], bh[ni], acc[mi][ni], 0, 0, 0);
        }
    }

    if (z < 2) {
        unsigned short* OH = z ? Kh : Qh;
#pragma unroll
        for (int mi = 0; mi < 4; ++mi)
#pragma unroll
            for (int ni = 0; ni < 4; ++ni) {
                const int col = n0 + wcol + ni * 16 + c;
#pragma unroll
                for (int r = 0; r < 4; ++r) {
                    const int row = m0 + wrow + mi * 16 + q * 4 + r;
                    OH[(size_t)row * DIM + col] = f2bf(acc[mi][ni][r]);
                }
            }
    } else {
#pragma unroll
        for (int mi = 0; mi < 4; ++mi) {
            const int mg = m0 + wrow + mi * 16 + q * 4;
            const int bb = mg >> 11, ss = mg & (SEQ - 1);
#pragma unroll
            for (int ni = 0; ni < 4; ++ni) {
                const int col = n0 + wcol + ni * 16 + c;
                u16x4v v;
                v.x = f2bf(acc[mi][ni][0]);
                v.y = f2bf(acc[mi][ni][1]);
                v.z = f2bf(acc[mi][ni][2]);
                v.w = f2bf(acc[mi][ni][3]);
                *(u16x4v*)(Vt + ((size_t)bb * DIM + col) * SEQ + ss) = v;
            }
        }
    }
}

// ---------------------------------------------------------------------------
// Scores GEMM, single-term MFMA, one batch: S = Qh Kh^T * SCALE, fp32 out.
// (Cross-term error sigma ~0.0016 in score units — below softmax visibility.)
// Skips tiles entirely above the diagonal.
// ---------------------------------------------------------------------------
__global__ __launch_bounds__(256) void scores_gemm1(
    const unsigned short* __restrict__ Qh, const unsigned short* __restrict__ Kh,
    float* __restrict__ S)
{
    if (blockIdx.y > blockIdx.x) return;
    __shared__ unsigned short Ah[128 * 40];
    __shared__ unsigned short Bh[128 * 40];
    const int i0 = blockIdx.x * 128, j0 = blockIdx.y * 128;
    const int tid = threadIdx.x;
    const int w = tid >> 6, lane = tid & 63, q = lane >> 4, c = lane & 15;
    const int wrow = (w >> 1) * 64, wcol = (w & 1) * 64;

    f32x4 acc[4][4];
#pragma unroll
    for (int a = 0; a < 4; ++a)
#pragma unroll
        for (int b = 0; b < 4; ++b) acc[a][b] = (f32x4){0.f, 0.f, 0.f, 0.f};

    const int srow = tid >> 1, sh = (tid & 1) * 16;
    for (int k0 = 0; k0 < DIM; k0 += 32) {
        __syncthreads();
        {
            const size_t ga = (size_t)(i0 + srow) * DIM + k0 + sh;
            const size_t gb = (size_t)(j0 + srow) * DIM + k0 + sh;
            unsigned short* sa = Ah + srow * 40 + sh;
            unsigned short* sb = Bh + srow * 40 + sh;
            *(u16x8v*)sa       = *(const u16x8v*)(Qh + ga);
            *(u16x8v*)(sa + 8) = *(const u16x8v*)(Qh + ga + 8);
            *(u16x8v*)sb       = *(const u16x8v*)(Kh + gb);
            *(u16x8v*)(sb + 8) = *(const u16x8v*)(Kh + gb + 8);
        }
        __syncthreads();
        bf16x8 ah[4], bh[4];
#pragma unroll
        for (int mi = 0; mi < 4; ++mi)
            ah[mi] = ldsld(Ah + (wrow + mi * 16 + c) * 40 + q * 8);
#pragma unroll
        for (int ni = 0; ni < 4; ++ni)
            bh[ni] = ldsld(Bh + (wcol + ni * 16 + c) * 40 + q * 8);
#pragma unroll
        for (int mi = 0; mi < 4; ++mi)
#pragma unroll
            for (int ni = 0; ni < 4; ++ni)
                acc[mi][ni] = __builtin_amdgcn_mfma_f32_16x16x32_bf16(ah[mi], bh[ni], acc[mi][ni], 0, 0, 0);
    }
#pragma unroll
    for (int mi = 0; mi < 4; ++mi)
#pragma unroll
        for (int ni = 0; ni < 4; ++ni) {
            const int col = j0 + wcol + ni * 16 + c;
#pragma unroll
            for (int r = 0; r < 4; ++r) {
                const int row = i0 + wrow + mi * 16 + q * 4 + r;
                S[(size_t)row * SEQ + col] = acc[mi][ni][r] * 0.03125f;
            }
        }
}

// ---------------------------------------------------------------------------
// Row-wise masked softmax: fp32 S -> bf16 P (full rows, masked -> 0).
// Faithful: j > i masked; j <= i masked iff S == 0.
// ---------------------------------------------------------------------------
__global__ __launch_bounds__(256) void softmax_row(
    const float* __restrict__ S, unsigned short* __restrict__ P)
{
    const int i = blockIdx.x, t = threadIdx.x;
    const int wid = t >> 6, lane = t & 63;
    __shared__ float redm[4], reds[4];
    float sv[8];
    float mx = -__builtin_inff();
#pragma unroll
    for (int u = 0; u < 8; ++u) {
        const int j = u * 256 + t;
        float s = -__builtin_inff();
        if (j <= i) {
            float x = S[(size_t)i * SEQ + j];
            s = (x == 0.f) ? -__builtin_inff() : x;
        }
        sv[u] = s;
        mx = fmaxf(mx, s);
    }
#pragma unroll
    for (int off = 1; off < 64; off <<= 1) mx = fmaxf(mx, __shfl_xor(mx, off));
    if (lane == 0) redm[wid] = mx;
    __syncthreads();
    const float M = fmaxf(fmaxf(redm[0], redm[1]), fmaxf(redm[2], redm[3]));
    float sum = 0.f;
#pragma unroll
    for (int u = 0; u < 8; ++u) {
        float e = __expf(sv[u] - M);
        sv[u] = e;
        sum += e;
    }
#pragma unroll
    for (int off = 1; off < 64; off <<= 1) sum += __shfl_xor(sum, off);
    if (lane == 0) reds[wid] = sum;
    __syncthreads();
    const float rinv = 1.f / (reds[0] + reds[1] + reds[2] + reds[3]);
#pragma unroll
    for (int u = 0; u < 8; ++u)
        P[(size_t)i * SEQ + u * 256 + t] = f2bf(sv[u] * rinv);
}

// ---------------------------------------------------------------------------
// out = P @ V via Vt (NT MFMA), fp32 store. Tile 64(i) x 128(d); k-loop
// truncated at causal bound i0+64.
// ---------------------------------------------------------------------------
__global__ __launch_bounds__(256) void pv_gemm(
    const unsigned short* __restrict__ Pm, const unsigned short* __restrict__ Vt,
    float* __restrict__ Out)
{
    __shared__ unsigned short Ps[64 * 40];
    __shared__ unsigned short Vs[128 * 40];
    const int i0 = blockIdx.x * 64, d0 = blockIdx.y * 128, b = blockIdx.z;
    const int tid = threadIdx.x;
    const int w = tid >> 6, lane = tid & 63, q = lane >> 4, c = lane & 15;
    const int wrow = (w >> 1) * 32, wcol = (w & 1) * 64;

    f32x4 acc[2][4];
#pragma unroll
    for (int a = 0; a < 2; ++a)
#pragma unroll
        for (int bq = 0; bq < 4; ++bq) acc[a][bq] = (f32x4){0.f, 0.f, 0.f, 0.f};

    const int njs = i0 / 32 + 2;
    const int prow = tid >> 2, pcol = (tid & 3) * 8;
    const int vrow = tid >> 1, vcol = (tid & 1) * 16;

    for (int ks = 0; ks < njs; ++ks) {
        const int j0 = ks * 32;
        __syncthreads();
        *(u16x8v*)(Ps + prow * 40 + pcol) =
            *(const u16x8v*)(Pm + ((size_t)b * SEQ + i0 + prow) * SEQ + j0 + pcol);
        {
            const unsigned short* g = Vt + ((size_t)b * DIM + d0 + vrow) * SEQ + j0 + vcol;
            unsigned short* sv_ = Vs + vrow * 40 + vcol;
            *(u16x8v*)sv_       = *(const u16x8v*)g;
            *(u16x8v*)(sv_ + 8) = *(const u16x8v*)(g + 8);
        }
        __syncthreads();
        bf16x8 bfr[4];
#pragma unroll
        for (int ni = 0; ni < 4; ++ni)
            bfr[ni] = ldsld(Vs + (wcol + ni * 16 + c) * 40 + q * 8);
#pragma unroll
        for (int mi = 0; mi < 2; ++mi) {
            bf16x8 a = ldsld(Ps + (wrow + mi * 16 + c) * 40 + q * 8);
#pragma unroll
            for (int ni = 0; ni < 4; ++ni)
                acc[mi][ni] = __builtin_amdgcn_mfma_f32_16x16x32_bf16(a, bfr[ni], acc[mi][ni], 0, 0, 0);
        }
    }
#pragma unroll
    for (int mi = 0; mi < 2; ++mi)
#pragma unroll
        for (int ni = 0; ni < 4; ++ni) {
            const int dcol = d0 + wcol + ni * 16 + c;
#pragma unroll
            for (int r = 0; r < 4; ++r) {
                const int i = i0 + wrow + mi * 16 + q * 4 + r;
                Out[((size_t)b * SEQ + i) * DIM + dcol] = acc[mi][ni][r];
            }
        }
}

extern "C" void kernel_launch(void* const* d_in, const int* in_sizes, int n_in,
                              void* d_out, int out_size, void* d_ws, size_t ws_size,
                              hipStream_t stream)
{
    (void)out_size; (void)ws_size;
    const float* X = nullptr;
    const float* Wv[3] = {nullptr, nullptr, nullptr};
    int nw = 0;
    for (int i = 0; i < n_in; ++i) {
        if (in_sizes[i] == (int)NBS)
            X = (const float*)d_in[i];
        else if (nw < 3)
            Wv[nw++] = (const float*)d_in[i];
    }

    unsigned short* ws = (unsigned short*)d_ws;
    unsigned short* Qh = ws;                 // 16 MB
    unsigned short* Kh = ws + NBS;           // 16 MB
    unsigned short* Vt = ws + 2 * NBS;       // 16 MB
    unsigned short* Xh = ws + 3 * NBS;       // consumed by qkv_gemm3
    unsigned short* Xl = ws + 4 * NBS;
    unsigned short* Pp = ws + 3 * NBS;       // P aliases Xh/Xl after qkv (32 MB)
    unsigned short* Wh = ws + 5 * NBS;       // 6 MB
    unsigned short* Wl = Wh + (size_t)3 * DIM * DIM;  // 6 MB
    float* Sf = (float*)(ws + 5 * NBS);      // S aliases Wh/Wl after qkv (16 MB)
    float* Out = (float*)d_out;

    split_f32<<<dim3((int)(NBS / 4 / 256)), 256, 0, stream>>>(X, Xh, Xl, (int)(NBS / 4));
    const int wn4 = DIM * DIM / 4;
    for (int z = 0; z < 3; ++z)
        split_f32<<<dim3(wn4 / 256), 256, 0, stream>>>(
            Wv[z], Wh + (size_t)z * DIM * DIM, Wl + (size_t)z * DIM * DIM, wn4);

    qkv_gemm3<<<dim3(64, 8, 3), 256, 0, stream>>>(Xh, Xl, Wh, Wl, Qh, Kh, Vt);

    for (int b = 0; b < BATCH; ++b) {
        const size_t bo = (size_t)b * SEQ * DIM;
        scores_gemm1<<<dim3(16, 16), 256, 0, stream>>>(Qh + bo, Kh + bo, Sf);
        softmax_row<<<dim3(SEQ), 256, 0, stream>>>(Sf, Pp + (size_t)b * SEQ * SEQ);
    }

    pv_gemm<<<dim3(32, 8, 4), 256, 0, stream>>>(Pp, Vt, Out);
}

// Round 9
// 429.175 us; speedup vs baseline: 1.2894x; 1.2894x over previous
//
#include <hip/hip_runtime.h>

typedef __bf16 bf16x8 __attribute__((ext_vector_type(8)));
typedef unsigned short u16x8v __attribute__((ext_vector_type(8)));
typedef unsigned short u16x4v __attribute__((ext_vector_type(4)));
typedef float f32x4 __attribute__((ext_vector_type(4)));

constexpr int SEQ = 2048;
constexpr int DIM = 1024;
constexpr int BATCH = 4;
constexpr size_t NBS = (size_t)BATCH * SEQ * DIM;  // 8388608

static __device__ __forceinline__ unsigned short f2bf(float f) {
    unsigned int u = __builtin_bit_cast(unsigned int, f);
    u += 0x7FFFu + ((u >> 16) & 1u);  // RNE
    return (unsigned short)(u >> 16);
}
static __device__ __forceinline__ float bf2f(unsigned short h) {
    return __builtin_bit_cast(float, (unsigned int)h << 16);
}
static __device__ __forceinline__ bf16x8 ldsld(const unsigned short* p) {
    return __builtin_bit_cast(bf16x8, *(const u16x8v*)p);
}

// ---------------------------------------------------------------------------
// fp32 -> bf16 hi + bf16 lo (lo = rne(x - hi)); 4 elems/thread.
// ---------------------------------------------------------------------------
__global__ __launch_bounds__(256) void split_f32(
    const float* __restrict__ in, unsigned short* __restrict__ hi,
    unsigned short* __restrict__ lo, int n4)
{
    int i = blockIdx.x * 256 + threadIdx.x;
    if (i >= n4) return;
    float4 f = ((const float4*)in)[i];
    u16x4v h, l;
    h.x = f2bf(f.x); l.x = f2bf(f.x - bf2f(h.x));
    h.y = f2bf(f.y); l.y = f2bf(f.y - bf2f(h.y));
    h.z = f2bf(f.z); l.z = f2bf(f.z - bf2f(h.z));
    h.w = f2bf(f.w); l.w = f2bf(f.w - bf2f(h.w));
    ((u16x4v*)hi)[i] = h;
    ((u16x4v*)lo)[i] = l;
}

// ---------------------------------------------------------------------------
// Q/K projection, split-3 MFMA (hh+hl+lh), NT, W [out,in]. 128x128 tile,
// 4 waves x 64x64 (4x4 MFMA 16x16x32). z=0 -> Qh, z=1 -> Kh (bf16 hi only).
// Dedicated kernel (no V path) keeps VGPR ~120 -> 4 blocks/CU.
// ---------------------------------------------------------------------------
__global__ __launch_bounds__(256) void qk_gemm3(
    const unsigned short* __restrict__ Xh, const unsigned short* __restrict__ Xl,
    const unsigned short* __restrict__ Wh, const unsigned short* __restrict__ Wl,
    unsigned short* __restrict__ Qh, unsigned short* __restrict__ Kh)
{
    __shared__ unsigned short Ah[128 * 40], Al[128 * 40];
    __shared__ unsigned short Bh[128 * 40], Bl[128 * 40];
    const int m0 = blockIdx.x * 128, n0 = blockIdx.y * 128, z = blockIdx.z;
    const unsigned short* Wzh = Wh + (size_t)z * DIM * DIM;
    const unsigned short* Wzl = Wl + (size_t)z * DIM * DIM;
    const int tid = threadIdx.x;
    const int w = tid >> 6, lane = tid & 63, q = lane >> 4, c = lane & 15;
    const int wrow = (w >> 1) * 64, wcol = (w & 1) * 64;

    f32x4 acc[4][4];
#pragma unroll
    for (int a = 0; a < 4; ++a)
#pragma unroll
        for (int b = 0; b < 4; ++b) acc[a][b] = (f32x4){0.f, 0.f, 0.f, 0.f};

    const int srow = tid >> 1, sh = (tid & 1) * 16;
    for (int k0 = 0; k0 < DIM; k0 += 32) {
        __syncthreads();
        {
            const size_t ga = (size_t)(m0 + srow) * DIM + k0 + sh;
            const size_t gb = (size_t)(n0 + srow) * DIM + k0 + sh;
            unsigned short* sa  = Ah + srow * 40 + sh;
            unsigned short* sal = Al + srow * 40 + sh;
            unsigned short* sb  = Bh + srow * 40 + sh;
            unsigned short* sbl = Bl + srow * 40 + sh;
            *(u16x8v*)sa        = *(const u16x8v*)(Xh + ga);
            *(u16x8v*)(sa + 8)  = *(const u16x8v*)(Xh + ga + 8);
            *(u16x8v*)sal       = *(const u16x8v*)(Xl + ga);
            *(u16x8v*)(sal + 8) = *(const u16x8v*)(Xl + ga + 8);
            *(u16x8v*)sb        = *(const u16x8v*)(Wzh + gb);
            *(u16x8v*)(sb + 8)  = *(const u16x8v*)(Wzh + gb + 8);
            *(u16x8v*)sbl       = *(const u16x8v*)(Wzl + gb);
            *(u16x8v*)(sbl + 8) = *(const u16x8v*)(Wzl + gb + 8);
        }
        __syncthreads();
        bf16x8 ah[4], al[4], bh[4], bl[4];
#pragma unroll
        for (int mi = 0; mi < 4; ++mi) {
            ah[mi] = ldsld(Ah + (wrow + mi * 16 + c) * 40 + q * 8);
            al[mi] = ldsld(Al + (wrow + mi * 16 + c) * 40 + q * 8);
        }
#pragma unroll
        for (int ni = 0; ni < 4; ++ni) {
            bh[ni] = ldsld(Bh + (wcol + ni * 16 + c) * 40 + q * 8);
            bl[ni] = ldsld(Bl + (wcol + ni * 16 + c) * 40 + q * 8);
        }
#pragma unroll
        for (int mi = 0; mi < 4; ++mi)
#pragma unroll
            for (int ni = 0; ni < 4; ++ni) {
                acc[mi][ni] = __builtin_amdgcn_mfma_f32_16x16x32_bf16(al[mi], bh[ni], acc[mi][ni], 0, 0, 0);
                acc[mi][ni] = __builtin_amdgcn_mfma_f32_16x16x32_bf16(ah[mi], bl[ni], acc[mi][ni], 0, 0, 0);
                acc[mi][ni] = __builtin_amdgcn_mfma_f32_16x16x32_bf16(ah[mi], bh[ni], acc[mi][ni], 0, 0, 0);
            }
    }

    unsigned short* OH = z ? Kh : Qh;
#pragma unroll
    for (int mi = 0; mi < 4; ++mi)
#pragma unroll
        for (int ni = 0; ni < 4; ++ni) {
            const int col = n0 + wcol + ni * 16 + c;
#pragma unroll
            for (int r = 0; r < 4; ++r) {
                const int row = m0 + wrow + mi * 16 + q * 4 + r;
                OH[(size_t)row * DIM + col] = f2bf(acc[mi][ni][r]);
            }
        }
}

// ---------------------------------------------------------------------------
// V projection, single hh MFMA term (V is bf16 downstream anyway).
// 128x128 tile; output stored transposed Vt[b][d][s].
// ---------------------------------------------------------------------------
__global__ __launch_bounds__(256) void v_gemm1(
    const unsigned short* __restrict__ Xh, const unsigned short* __restrict__ Wh,
    unsigned short* __restrict__ Vt)
{
    __shared__ unsigned short Ah[128 * 40];
    __shared__ unsigned short Bh[128 * 40];
    const int m0 = blockIdx.x * 128, n0 = blockIdx.y * 128;
    const int tid = threadIdx.x;
    const int w = tid >> 6, lane = tid & 63, q = lane >> 4, c = lane & 15;
    const int wrow = (w >> 1) * 64, wcol = (w & 1) * 64;

    f32x4 acc[4][4];
#pragma unroll
    for (int a = 0; a < 4; ++a)
#pragma unroll
        for (int b = 0; b < 4; ++b) acc[a][b] = (f32x4){0.f, 0.f, 0.f, 0.f};

    const int srow = tid >> 1, sh = (tid & 1) * 16;
    for (int k0 = 0; k0 < DIM; k0 += 32) {
        __syncthreads();
        {
            const size_t ga = (size_t)(m0 + srow) * DIM + k0 + sh;
            const size_t gb = (size_t)(n0 + srow) * DIM + k0 + sh;
            unsigned short* sa = Ah + srow * 40 + sh;
            unsigned short* sb = Bh + srow * 40 + sh;
            *(u16x8v*)sa       = *(const u16x8v*)(Xh + ga);
            *(u16x8v*)(sa + 8) = *(const u16x8v*)(Xh + ga + 8);
            *(u16x8v*)sb       = *(const u16x8v*)(Wh + gb);
            *(u16x8v*)(sb + 8) = *(const u16x8v*)(Wh + gb + 8);
        }
        __syncthreads();
        bf16x8 ah[4], bh[4];
#pragma unroll
        for (int mi = 0; mi < 4; ++mi)
            ah[mi] = ldsld(Ah + (wrow + mi * 16 + c) * 40 + q * 8);
#pragma unroll
        for (int ni = 0; ni < 4; ++ni)
            bh[ni] = ldsld(Bh + (wcol + ni * 16 + c) * 40 + q * 8);
#pragma unroll
        for (int mi = 0; mi < 4; ++mi)
#pragma unroll
            for (int ni = 0; ni < 4; ++ni)
                acc[mi][ni] = __builtin_amdgcn_mfma_f32_16x16x32_bf16(ah[mi], bh[ni], acc[mi][ni], 0, 0, 0);
    }
#pragma unroll
    for (int mi = 0; mi < 4; ++mi) {
        const int mg = m0 + wrow + mi * 16 + q * 4;
        const int bb = mg >> 11, ss = mg & (SEQ - 1);
#pragma unroll
        for (int ni = 0; ni < 4; ++ni) {
            const int col = n0 + wcol + ni * 16 + c;
            u16x4v v;
            v.x = f2bf(acc[mi][ni][0]);
            v.y = f2bf(acc[mi][ni][1]);
            v.z = f2bf(acc[mi][ni][2]);
            v.w = f2bf(acc[mi][ni][3]);
            *(u16x4v*)(Vt + ((size_t)bb * DIM + col) * SEQ + ss) = v;
        }
    }
}

// ---------------------------------------------------------------------------
// Scores GEMM, single-term MFMA, one batch: S = Qh Kh^T * SCALE, fp32 out.
// Skips tiles entirely above the diagonal.
// ---------------------------------------------------------------------------
__global__ __launch_bounds__(256) void scores_gemm1(
    const unsigned short* __restrict__ Qh, const unsigned short* __restrict__ Kh,
    float* __restrict__ S)
{
    if (blockIdx.y > blockIdx.x) return;
    __shared__ unsigned short Ah[128 * 40];
    __shared__ unsigned short Bh[128 * 40];
    const int i0 = blockIdx.x * 128, j0 = blockIdx.y * 128;
    const int tid = threadIdx.x;
    const int w = tid >> 6, lane = tid & 63, q = lane >> 4, c = lane & 15;
    const int wrow = (w >> 1) * 64, wcol = (w & 1) * 64;

    f32x4 acc[4][4];
#pragma unroll
    for (int a = 0; a < 4; ++a)
#pragma unroll
        for (int b = 0; b < 4; ++b) acc[a][b] = (f32x4){0.f, 0.f, 0.f, 0.f};

    const int srow = tid >> 1, sh = (tid & 1) * 16;
    for (int k0 = 0; k0 < DIM; k0 += 32) {
        __syncthreads();
        {
            const size_t ga = (size_t)(i0 + srow) * DIM + k0 + sh;
            const size_t gb = (size_t)(j0 + srow) * DIM + k0 + sh;
            unsigned short* sa = Ah + srow * 40 + sh;
            unsigned short* sb = Bh + srow * 40 + sh;
            *(u16x8v*)sa       = *(const u16x8v*)(Qh + ga);
            *(u16x8v*)(sa + 8) = *(const u16x8v*)(Qh + ga + 8);
            *(u16x8v*)sb       = *(const u16x8v*)(Kh + gb);
            *(u16x8v*)(sb + 8) = *(const u16x8v*)(Kh + gb + 8);
        }
        __syncthreads();
        bf16x8 ah[4], bh[4];
#pragma unroll
        for (int mi = 0; mi < 4; ++mi)
            ah[mi] = ldsld(Ah + (wrow + mi * 16 + c) * 40 + q * 8);
#pragma unroll
        for (int ni = 0; ni < 4; ++ni)
            bh[ni] = ldsld(Bh + (wcol + ni * 16 + c) * 40 + q * 8);
#pragma unroll
        for (int mi = 0; mi < 4; ++mi)
#pragma unroll
            for (int ni = 0; ni < 4; ++ni)
                acc[mi][ni] = __builtin_amdgcn_mfma_f32_16x16x32_bf16(ah[mi], bh[ni], acc[mi][ni], 0, 0, 0);
    }
#pragma unroll
    for (int mi = 0; mi < 4; ++mi)
#pragma unroll
        for (int ni = 0; ni < 4; ++ni) {
            const int col = j0 + wcol + ni * 16 + c;
#pragma unroll
            for (int r = 0; r < 4; ++r) {
                const int row = i0 + wrow + mi * 16 + q * 4 + r;
                S[(size_t)row * SEQ + col] = acc[mi][ni][r] * 0.03125f;
            }
        }
}

// ---------------------------------------------------------------------------
// Row-wise masked softmax: fp32 S -> bf16 P (full rows, masked -> 0).
// Faithful: j > i masked; j <= i masked iff S == 0.
// ---------------------------------------------------------------------------
__global__ __launch_bounds__(256) void softmax_row(
    const float* __restrict__ S, unsigned short* __restrict__ P)
{
    const int i = blockIdx.x, t = threadIdx.x;
    const int wid = t >> 6, lane = t & 63;
    __shared__ float redm[4], reds[4];
    float sv[8];
    float mx = -__builtin_inff();
#pragma unroll
    for (int u = 0; u < 8; ++u) {
        const int j = u * 256 + t;
        float s = -__builtin_inff();
        if (j <= i) {
            float x = S[(size_t)i * SEQ + j];
            s = (x == 0.f) ? -__builtin_inff() : x;
        }
        sv[u] = s;
        mx = fmaxf(mx, s);
    }
#pragma unroll
    for (int off = 1; off < 64; off <<= 1) mx = fmaxf(mx, __shfl_xor(mx, off));
    if (lane == 0) redm[wid] = mx;
    __syncthreads();
    const float M = fmaxf(fmaxf(redm[0], redm[1]), fmaxf(redm[2], redm[3]));
    float sum = 0.f;
#pragma unroll
    for (int u = 0; u < 8; ++u) {
        float e = __expf(sv[u] - M);
        sv[u] = e;
        sum += e;
    }
#pragma unroll
    for (int off = 1; off < 64; off <<= 1) sum += __shfl_xor(sum, off);
    if (lane == 0) reds[wid] = sum;
    __syncthreads();
    const float rinv = 1.f / (reds[0] + reds[1] + reds[2] + reds[3]);
#pragma unroll
    for (int u = 0; u < 8; ++u)
        P[(size_t)i * SEQ + u * 256 + t] = f2bf(sv[u] * rinv);
}

// ---------------------------------------------------------------------------
// out = P @ V via Vt (NT MFMA), fp32 store. Tile 64(i) x 128(d); k-loop
// truncated at causal bound i0+64.
// ---------------------------------------------------------------------------
__global__ __launch_bounds__(256) void pv_gemm(
    const unsigned short* __restrict__ Pm, const unsigned short* __restrict__ Vt,
    float* __restrict__ Out)
{
    __shared__ unsigned short Ps[64 * 40];
    __shared__ unsigned short Vs[128 * 40];
    const int i0 = blockIdx.x * 64, d0 = blockIdx.y * 128, b = blockIdx.z;
    const int tid = threadIdx.x;
    const int w = tid >> 6, lane = tid & 63, q = lane >> 4, c = lane & 15;
    const int wrow = (w >> 1) * 32, wcol = (w & 1) * 64;

    f32x4 acc[2][4];
#pragma unroll
    for (int a = 0; a < 2; ++a)
#pragma unroll
        for (int bq = 0; bq < 4; ++bq) acc[a][bq] = (f32x4){0.f, 0.f, 0.f, 0.f};

    const int njs = i0 / 32 + 2;
    const int prow = tid >> 2, pcol = (tid & 3) * 8;
    const int vrow = tid >> 1, vcol = (tid & 1) * 16;

    for (int ks = 0; ks < njs; ++ks) {
        const int j0 = ks * 32;
        __syncthreads();
        *(u16x8v*)(Ps + prow * 40 + pcol) =
            *(const u16x8v*)(Pm + ((size_t)b * SEQ + i0 + prow) * SEQ + j0 + pcol);
        {
            const unsigned short* g = Vt + ((size_t)b * DIM + d0 + vrow) * SEQ + j0 + vcol;
            unsigned short* sv_ = Vs + vrow * 40 + vcol;
            *(u16x8v*)sv_       = *(const u16x8v*)g;
            *(u16x8v*)(sv_ + 8) = *(const u16x8v*)(g + 8);
        }
        __syncthreads();
        bf16x8 bfr[4];
#pragma unroll
        for (int ni = 0; ni < 4; ++ni)
            bfr[ni] = ldsld(Vs + (wcol + ni * 16 + c) * 40 + q * 8);
#pragma unroll
        for (int mi = 0; mi < 2; ++mi) {
            bf16x8 a = ldsld(Ps + (wrow + mi * 16 + c) * 40 + q * 8);
#pragma unroll
            for (int ni = 0; ni < 4; ++ni)
                acc[mi][ni] = __builtin_amdgcn_mfma_f32_16x16x32_bf16(a, bfr[ni], acc[mi][ni], 0, 0, 0);
        }
    }
#pragma unroll
    for (int mi = 0; mi < 2; ++mi)
#pragma unroll
        for (int ni = 0; ni < 4; ++ni) {
            const int dcol = d0 + wcol + ni * 16 + c;
#pragma unroll
            for (int r = 0; r < 4; ++r) {
                const int i = i0 + wrow + mi * 16 + q * 4 + r;
                Out[((size_t)b * SEQ + i) * DIM + dcol] = acc[mi][ni][r];
            }
        }
}

extern "C" void kernel_launch(void* const* d_in, const int* in_sizes, int n_in,
                              void* d_out, int out_size, void* d_ws, size_t ws_size,
                              hipStream_t stream)
{
    (void)out_size; (void)ws_size;
    const float* X = nullptr;
    const float* Wv[3] = {nullptr, nullptr, nullptr};
    int nw = 0;
    for (int i = 0; i < n_in; ++i) {
        if (in_sizes[i] == (int)NBS)
            X = (const float*)d_in[i];
        else if (nw < 3)
            Wv[nw++] = (const float*)d_in[i];
    }

    unsigned short* ws = (unsigned short*)d_ws;
    unsigned short* Qh = ws;                 // 16 MB
    unsigned short* Kh = ws + NBS;           // 16 MB
    unsigned short* Vt = ws + 2 * NBS;       // 16 MB
    unsigned short* Xh = ws + 3 * NBS;       // consumed by qk/v gemms
    unsigned short* Xl = ws + 4 * NBS;
    unsigned short* Pp = ws + 3 * NBS;       // P aliases Xh/Xl after qkv (32 MB)
    unsigned short* Wh = ws + 5 * NBS;       // 6 MB
    unsigned short* Wl = Wh + (size_t)3 * DIM * DIM;  // 6 MB
    float* Sf = (float*)(ws + 5 * NBS);      // S aliases Wh/Wl after qkv (16 MB)
    float* Out = (float*)d_out;

    split_f32<<<dim3((int)(NBS / 4 / 256)), 256, 0, stream>>>(X, Xh, Xl, (int)(NBS / 4));
    const int wn4 = DIM * DIM / 4;
    for (int z = 0; z < 3; ++z)
        split_f32<<<dim3(wn4 / 256), 256, 0, stream>>>(
            Wv[z], Wh + (size_t)z * DIM * DIM, Wl + (size_t)z * DIM * DIM, wn4);

    qk_gemm3<<<dim3(64, 8, 2), 256, 0, stream>>>(Xh, Xl, Wh, Wl, Qh, Kh);
    v_gemm1<<<dim3(64, 8), 256, 0, stream>>>(Xh, Wh + (size_t)2 * DIM * DIM, Vt);

    for (int b = 0; b < BATCH; ++b) {
        const size_t bo = (size_t)b * SEQ * DIM;
        scores_gemm1<<<dim3(16, 16), 256, 0, stream>>>(Qh + bo, Kh + bo, Sf);
        softmax_row<<<dim3(SEQ), 256, 0, stream>>>(Sf, Pp + (size_t)b * SEQ * SEQ);
    }

    pv_gemm<<<dim3(32, 8, 4), 256, 0, stream>>>(Pp, Vt, Out);
}

// Round 10
// 373.834 us; speedup vs baseline: 1.4802x; 1.1480x over previous
//
#include <hip/hip_runtime.h>

typedef __bf16 bf16x8 __attribute__((ext_vector_type(8)));
typedef unsigned short u16x8v __attribute__((ext_vector_type(8)));
typedef unsigned short u16x4v __attribute__((ext_vector_type(4)));
typedef float f32x4 __attribute__((ext_vector_type(4)));

constexpr int SEQ = 2048;
constexpr int DIM = 1024;
constexpr int BATCH = 4;
constexpr size_t NBS = (size_t)BATCH * SEQ * DIM;  // 8388608

static __device__ __forceinline__ unsigned short f2bf(float f) {
    unsigned int u = __builtin_bit_cast(unsigned int, f);
    u += 0x7FFFu + ((u >> 16) & 1u);  // RNE
    return (unsigned short)(u >> 16);
}
static __device__ __forceinline__ float bf2f(unsigned short h) {
    return __builtin_bit_cast(float, (unsigned int)h << 16);
}
static __device__ __forceinline__ bf16x8 ldsld(const unsigned short* p) {
    return __builtin_bit_cast(bf16x8, *(const u16x8v*)p);
}

// ---------------------------------------------------------------------------
// fp32 -> bf16 hi + bf16 lo (lo = rne(x - hi)); 4 elems/thread.
// ---------------------------------------------------------------------------
__global__ __launch_bounds__(256) void split_f32(
    const float* __restrict__ in, unsigned short* __restrict__ hi,
    unsigned short* __restrict__ lo, int n4)
{
    int i = blockIdx.x * 256 + threadIdx.x;
    if (i >= n4) return;
    float4 f = ((const float4*)in)[i];
    u16x4v h, l;
    h.x = f2bf(f.x); l.x = f2bf(f.x - bf2f(h.x));
    h.y = f2bf(f.y); l.y = f2bf(f.y - bf2f(h.y));
    h.z = f2bf(f.z); l.z = f2bf(f.z - bf2f(h.z));
    h.w = f2bf(f.w); l.w = f2bf(f.w - bf2f(h.w));
    ((u16x4v*)hi)[i] = h;
    ((u16x4v*)lo)[i] = l;
}

// ---------------------------------------------------------------------------
// Q/K projection, split-3 MFMA (hh+hl+lh), NT, W [out,in]. 128x128 tile,
// 4 waves x 64x64 (4x4 MFMA 16x16x32). z=0 -> Qh, z=1 -> Kh (bf16 hi only).
// VGPR ~92 -> plateau-level occupancy (do not merge V in: round-8 regression).
// ---------------------------------------------------------------------------
__global__ __launch_bounds__(256) void qk_gemm3(
    const unsigned short* __restrict__ Xh, const unsigned short* __restrict__ Xl,
    const unsigned short* __restrict__ Wh, const unsigned short* __restrict__ Wl,
    unsigned short* __restrict__ Qh, unsigned short* __restrict__ Kh)
{
    __shared__ unsigned short Ah[128 * 40], Al[128 * 40];
    __shared__ unsigned short Bh[128 * 40], Bl[128 * 40];
    const int m0 = blockIdx.x * 128, n0 = blockIdx.y * 128, z = blockIdx.z;
    const unsigned short* Wzh = Wh + (size_t)z * DIM * DIM;
    const unsigned short* Wzl = Wl + (size_t)z * DIM * DIM;
    const int tid = threadIdx.x;
    const int w = tid >> 6, lane = tid & 63, q = lane >> 4, c = lane & 15;
    const int wrow = (w >> 1) * 64, wcol = (w & 1) * 64;

    f32x4 acc[4][4];
#pragma unroll
    for (int a = 0; a < 4; ++a)
#pragma unroll
        for (int b = 0; b < 4; ++b) acc[a][b] = (f32x4){0.f, 0.f, 0.f, 0.f};

    const int srow = tid >> 1, sh = (tid & 1) * 16;
    for (int k0 = 0; k0 < DIM; k0 += 32) {
        __syncthreads();
        {
            const size_t ga = (size_t)(m0 + srow) * DIM + k0 + sh;
            const size_t gb = (size_t)(n0 + srow) * DIM + k0 + sh;
            unsigned short* sa  = Ah + srow * 40 + sh;
            unsigned short* sal = Al + srow * 40 + sh;
            unsigned short* sb  = Bh + srow * 40 + sh;
            unsigned short* sbl = Bl + srow * 40 + sh;
            *(u16x8v*)sa        = *(const u16x8v*)(Xh + ga);
            *(u16x8v*)(sa + 8)  = *(const u16x8v*)(Xh + ga + 8);
            *(u16x8v*)sal       = *(const u16x8v*)(Xl + ga);
            *(u16x8v*)(sal + 8) = *(const u16x8v*)(Xl + ga + 8);
            *(u16x8v*)sb        = *(const u16x8v*)(Wzh + gb);
            *(u16x8v*)(sb + 8)  = *(const u16x8v*)(Wzh + gb + 8);
            *(u16x8v*)sbl       = *(const u16x8v*)(Wzl + gb);
            *(u16x8v*)(sbl + 8) = *(const u16x8v*)(Wzl + gb + 8);
        }
        __syncthreads();
        bf16x8 ah[4], al[4], bh[4], bl[4];
#pragma unroll
        for (int mi = 0; mi < 4; ++mi) {
            ah[mi] = ldsld(Ah + (wrow + mi * 16 + c) * 40 + q * 8);
            al[mi] = ldsld(Al + (wrow + mi * 16 + c) * 40 + q * 8);
        }
#pragma unroll
        for (int ni = 0; ni < 4; ++ni) {
            bh[ni] = ldsld(Bh + (wcol + ni * 16 + c) * 40 + q * 8);
            bl[ni] = ldsld(Bl + (wcol + ni * 16 + c) * 40 + q * 8);
        }
#pragma unroll
        for (int mi = 0; mi < 4; ++mi)
#pragma unroll
            for (int ni = 0; ni < 4; ++ni) {
                acc[mi][ni] = __builtin_amdgcn_mfma_f32_16x16x32_bf16(al[mi], bh[ni], acc[mi][ni], 0, 0, 0);
                acc[mi][ni] = __builtin_amdgcn_mfma_f32_16x16x32_bf16(ah[mi], bl[ni], acc[mi][ni], 0, 0, 0);
                acc[mi][ni] = __builtin_amdgcn_mfma_f32_16x16x32_bf16(ah[mi], bh[ni], acc[mi][ni], 0, 0, 0);
            }
    }

    unsigned short* OH = z ? Kh : Qh;
#pragma unroll
    for (int mi = 0; mi < 4; ++mi)
#pragma unroll
        for (int ni = 0; ni < 4; ++ni) {
            const int col = n0 + wcol + ni * 16 + c;
#pragma unroll
            for (int r = 0; r < 4; ++r) {
                const int row = m0 + wrow + mi * 16 + q * 4 + r;
                OH[(size_t)row * DIM + col] = f2bf(acc[mi][ni][r]);
            }
        }
}

// ---------------------------------------------------------------------------
// V projection, single hh MFMA term. Output stored transposed Vt[b][d][s].
// ---------------------------------------------------------------------------
__global__ __launch_bounds__(256) void v_gemm1(
    const unsigned short* __restrict__ Xh, const unsigned short* __restrict__ Wh,
    unsigned short* __restrict__ Vt)
{
    __shared__ unsigned short Ah[128 * 40];
    __shared__ unsigned short Bh[128 * 40];
    const int m0 = blockIdx.x * 128, n0 = blockIdx.y * 128;
    const int tid = threadIdx.x;
    const int w = tid >> 6, lane = tid & 63, q = lane >> 4, c = lane & 15;
    const int wrow = (w >> 1) * 64, wcol = (w & 1) * 64;

    f32x4 acc[4][4];
#pragma unroll
    for (int a = 0; a < 4; ++a)
#pragma unroll
        for (int b = 0; b < 4; ++b) acc[a][b] = (f32x4){0.f, 0.f, 0.f, 0.f};

    const int srow = tid >> 1, sh = (tid & 1) * 16;
    for (int k0 = 0; k0 < DIM; k0 += 32) {
        __syncthreads();
        {
            const size_t ga = (size_t)(m0 + srow) * DIM + k0 + sh;
            const size_t gb = (size_t)(n0 + srow) * DIM + k0 + sh;
            unsigned short* sa = Ah + srow * 40 + sh;
            unsigned short* sb = Bh + srow * 40 + sh;
            *(u16x8v*)sa       = *(const u16x8v*)(Xh + ga);
            *(u16x8v*)(sa + 8) = *(const u16x8v*)(Xh + ga + 8);
            *(u16x8v*)sb       = *(const u16x8v*)(Wh + gb);
            *(u16x8v*)(sb + 8) = *(const u16x8v*)(Wh + gb + 8);
        }
        __syncthreads();
        bf16x8 ah[4], bh[4];
#pragma unroll
        for (int mi = 0; mi < 4; ++mi)
            ah[mi] = ldsld(Ah + (wrow + mi * 16 + c) * 40 + q * 8);
#pragma unroll
        for (int ni = 0; ni < 4; ++ni)
            bh[ni] = ldsld(Bh + (wcol + ni * 16 + c) * 40 + q * 8);
#pragma unroll
        for (int mi = 0; mi < 4; ++mi)
#pragma unroll
            for (int ni = 0; ni < 4; ++ni)
                acc[mi][ni] = __builtin_amdgcn_mfma_f32_16x16x32_bf16(ah[mi], bh[ni], acc[mi][ni], 0, 0, 0);
    }
#pragma unroll
    for (int mi = 0; mi < 4; ++mi) {
        const int mg = m0 + wrow + mi * 16 + q * 4;
        const int bb = mg >> 11, ss = mg & (SEQ - 1);
#pragma unroll
        for (int ni = 0; ni < 4; ++ni) {
            const int col = n0 + wcol + ni * 16 + c;
            u16x4v v;
            v.x = f2bf(acc[mi][ni][0]);
            v.y = f2bf(acc[mi][ni][1]);
            v.z = f2bf(acc[mi][ni][2]);
            v.w = f2bf(acc[mi][ni][3]);
            *(u16x4v*)(Vt + ((size_t)bb * DIM + col) * SEQ + ss) = v;
        }
    }
}

// ---------------------------------------------------------------------------
// Scores GEMM, ALL batches in one launch: S = Qh Kh^T * SCALE, bf16 out.
// Grid (16,16,BATCH); skips tiles entirely above the diagonal.
// ---------------------------------------------------------------------------
__global__ __launch_bounds__(256) void scores_gemm1b(
    const unsigned short* __restrict__ Q, const unsigned short* __restrict__ K,
    unsigned short* __restrict__ S)
{
    if (blockIdx.y > blockIdx.x) return;
    __shared__ unsigned short Ah[128 * 40];
    __shared__ unsigned short Bh[128 * 40];
    const int i0 = blockIdx.x * 128, j0 = blockIdx.y * 128, b = blockIdx.z;
    const unsigned short* Qb = Q + (size_t)b * SEQ * DIM;
    const unsigned short* Kb = K + (size_t)b * SEQ * DIM;
    unsigned short* Sb = S + (size_t)b * SEQ * SEQ;
    const int tid = threadIdx.x;
    const int w = tid >> 6, lane = tid & 63, q = lane >> 4, c = lane & 15;
    const int wrow = (w >> 1) * 64, wcol = (w & 1) * 64;

    f32x4 acc[4][4];
#pragma unroll
    for (int a = 0; a < 4; ++a)
#pragma unroll
        for (int bq = 0; bq < 4; ++bq) acc[a][bq] = (f32x4){0.f, 0.f, 0.f, 0.f};

    const int srow = tid >> 1, sh = (tid & 1) * 16;
    for (int k0 = 0; k0 < DIM; k0 += 32) {
        __syncthreads();
        {
            const size_t ga = (size_t)(i0 + srow) * DIM + k0 + sh;
            const size_t gb = (size_t)(j0 + srow) * DIM + k0 + sh;
            unsigned short* sa = Ah + srow * 40 + sh;
            unsigned short* sb = Bh + srow * 40 + sh;
            *(u16x8v*)sa       = *(const u16x8v*)(Qb + ga);
            *(u16x8v*)(sa + 8) = *(const u16x8v*)(Qb + ga + 8);
            *(u16x8v*)sb       = *(const u16x8v*)(Kb + gb);
            *(u16x8v*)(sb + 8) = *(const u16x8v*)(Kb + gb + 8);
        }
        __syncthreads();
        bf16x8 ah[4], bh[4];
#pragma unroll
        for (int mi = 0; mi < 4; ++mi)
            ah[mi] = ldsld(Ah + (wrow + mi * 16 + c) * 40 + q * 8);
#pragma unroll
        for (int ni = 0; ni < 4; ++ni)
            bh[ni] = ldsld(Bh + (wcol + ni * 16 + c) * 40 + q * 8);
#pragma unroll
        for (int mi = 0; mi < 4; ++mi)
#pragma unroll
            for (int ni = 0; ni < 4; ++ni)
                acc[mi][ni] = __builtin_amdgcn_mfma_f32_16x16x32_bf16(ah[mi], bh[ni], acc[mi][ni], 0, 0, 0);
    }
#pragma unroll
    for (int mi = 0; mi < 4; ++mi)
#pragma unroll
        for (int ni = 0; ni < 4; ++ni) {
            const int col = j0 + wcol + ni * 16 + c;
#pragma unroll
            for (int r = 0; r < 4; ++r) {
                const int row = i0 + wrow + mi * 16 + q * 4 + r;
                Sb[(size_t)row * SEQ + col] = f2bf(acc[mi][ni][r] * 0.03125f);
            }
        }
}

// ---------------------------------------------------------------------------
// Row-wise masked softmax, ALL batches: bf16 S -> bf16 P (full rows).
// Faithful: j > i masked; j <= i masked iff S == 0. Grid (SEQ, BATCH).
// ---------------------------------------------------------------------------
__global__ __launch_bounds__(256) void softmax_row_b(
    const unsigned short* __restrict__ S, unsigned short* __restrict__ P)
{
    const int i = blockIdx.x, t = threadIdx.x;
    const size_t ro = ((size_t)blockIdx.y * SEQ + i) * SEQ;
    const int wid = t >> 6, lane = t & 63;
    __shared__ float redm[4], reds[4];
    float sv[8];
    float mx = -__builtin_inff();
#pragma unroll
    for (int u = 0; u < 8; ++u) {
        const int j = u * 256 + t;
        float s = -__builtin_inff();
        if (j <= i) {
            float x = bf2f(S[ro + j]);
            s = (x == 0.f) ? -__builtin_inff() : x;
        }
        sv[u] = s;
        mx = fmaxf(mx, s);
    }
#pragma unroll
    for (int off = 1; off < 64; off <<= 1) mx = fmaxf(mx, __shfl_xor(mx, off));
    if (lane == 0) redm[wid] = mx;
    __syncthreads();
    const float M = fmaxf(fmaxf(redm[0], redm[1]), fmaxf(redm[2], redm[3]));
    float sum = 0.f;
#pragma unroll
    for (int u = 0; u < 8; ++u) {
        float e = __expf(sv[u] - M);
        sv[u] = e;
        sum += e;
    }
#pragma unroll
    for (int off = 1; off < 64; off <<= 1) sum += __shfl_xor(sum, off);
    if (lane == 0) reds[wid] = sum;
    __syncthreads();
    const float rinv = 1.f / (reds[0] + reds[1] + reds[2] + reds[3]);
#pragma unroll
    for (int u = 0; u < 8; ++u)
        P[ro + u * 256 + t] = f2bf(sv[u] * rinv);
}

// ---------------------------------------------------------------------------
// out = P @ V via Vt (NT MFMA), fp32 store. 128x128 tile (4x4 acc, same
// MFMA:staging ratio as scores); k-loop truncated at causal bound i0+128.
// ---------------------------------------------------------------------------
__global__ __launch_bounds__(256) void pv_gemm(
    const unsigned short* __restrict__ Pm, const unsigned short* __restrict__ Vt,
    float* __restrict__ Out)
{
    __shared__ unsigned short Ps[128 * 40];
    __shared__ unsigned short Vs[128 * 40];
    const int i0 = blockIdx.x * 128, d0 = blockIdx.y * 128, b = blockIdx.z;
    const int tid = threadIdx.x;
    const int w = tid >> 6, lane = tid & 63, q = lane >> 4, c = lane & 15;
    const int wrow = (w >> 1) * 64, wcol = (w & 1) * 64;

    f32x4 acc[4][4];
#pragma unroll
    for (int a = 0; a < 4; ++a)
#pragma unroll
        for (int bq = 0; bq < 4; ++bq) acc[a][bq] = (f32x4){0.f, 0.f, 0.f, 0.f};

    const int njs = i0 / 32 + 4;  // covers cols < i0+128
    const int srow = tid >> 1, sh = (tid & 1) * 16;

    for (int ks = 0; ks < njs; ++ks) {
        const int j0 = ks * 32;
        __syncthreads();
        {
            unsigned short* sp = Ps + srow * 40 + sh;
            const unsigned short* gp = Pm + ((size_t)b * SEQ + i0 + srow) * SEQ + j0 + sh;
            *(u16x8v*)sp       = *(const u16x8v*)gp;
            *(u16x8v*)(sp + 8) = *(const u16x8v*)(gp + 8);
            const unsigned short* gv = Vt + ((size_t)b * DIM + d0 + srow) * SEQ + j0 + sh;
            unsigned short* sv_ = Vs + srow * 40 + sh;
            *(u16x8v*)sv_       = *(const u16x8v*)gv;
            *(u16x8v*)(sv_ + 8) = *(const u16x8v*)(gv + 8);
        }
        __syncthreads();
        bf16x8 ah[4], bh[4];
#pragma unroll
        for (int mi = 0; mi < 4; ++mi)
            ah[mi] = ldsld(Ps + (wrow + mi * 16 + c) * 40 + q * 8);
#pragma unroll
        for (int ni = 0; ni < 4; ++ni)
            bh[ni] = ldsld(Vs + (wcol + ni * 16 + c) * 40 + q * 8);
#pragma unroll
        for (int mi = 0; mi < 4; ++mi)
#pragma unroll
            for (int ni = 0; ni < 4; ++ni)
                acc[mi][ni] = __builtin_amdgcn_mfma_f32_16x16x32_bf16(ah[mi], bh[ni], acc[mi][ni], 0, 0, 0);
    }
#pragma unroll
    for (int mi = 0; mi < 4; ++mi)
#pragma unroll
        for (int ni = 0; ni < 4; ++ni) {
            const int dcol = d0 + wcol + ni * 16 + c;
#pragma unroll
            for (int r = 0; r < 4; ++r) {
                const int i = i0 + wrow + mi * 16 + q * 4 + r;
                Out[((size_t)b * SEQ + i) * DIM + dcol] = acc[mi][ni][r];
            }
        }
}

extern "C" void kernel_launch(void* const* d_in, const int* in_sizes, int n_in,
                              void* d_out, int out_size, void* d_ws, size_t ws_size,
                              hipStream_t stream)
{
    (void)out_size; (void)ws_size;
    const float* X = nullptr;
    const float* Wv[3] = {nullptr, nullptr, nullptr};
    int nw = 0;
    for (int i = 0; i < n_in; ++i) {
        if (in_sizes[i] == (int)NBS)
            X = (const float*)d_in[i];
        else if (nw < 3)
            Wv[nw++] = (const float*)d_in[i];
    }

    unsigned short* ws = (unsigned short*)d_ws;
    unsigned short* Qh = ws;                 // 16 MB
    unsigned short* Kh = ws + NBS;           // 16 MB
    unsigned short* Vt = ws + 2 * NBS;       // 16 MB
    unsigned short* Xh = ws + 3 * NBS;       // consumed by qk/v gemms
    unsigned short* Xl = ws + 4 * NBS;
    unsigned short* Pp = ws + 3 * NBS;       // P aliases Xh/Xl after qkv (32 MB)
    unsigned short* Sb = ws + 5 * NBS;       // bf16 S, all batches (32 MB)
    unsigned short* Wh = ws + 7 * NBS;       // 6 MB
    unsigned short* Wl = Wh + (size_t)3 * DIM * DIM;  // 6 MB  (peak 124 MB)
    float* Out = (float*)d_out;

    split_f32<<<dim3((int)(NBS / 4 / 256)), 256, 0, stream>>>(X, Xh, Xl, (int)(NBS / 4));
    const int wn4 = DIM * DIM / 4;
    for (int z = 0; z < 3; ++z)
        split_f32<<<dim3(wn4 / 256), 256, 0, stream>>>(
            Wv[z], Wh + (size_t)z * DIM * DIM, Wl + (size_t)z * DIM * DIM, wn4);

    qk_gemm3<<<dim3(64, 8, 2), 256, 0, stream>>>(Xh, Xl, Wh, Wl, Qh, Kh);
    v_gemm1<<<dim3(64, 8), 256, 0, stream>>>(Xh, Wh + (size_t)2 * DIM * DIM, Vt);

    scores_gemm1b<<<dim3(16, 16, BATCH), 256, 0, stream>>>(Qh, Kh, Sb);
    softmax_row_b<<<dim3(SEQ, BATCH), 256, 0, stream>>>(Sb, Pp);

    pv_gemm<<<dim3(16, 8, BATCH), 256, 0, stream>>>(Pp, Vt, Out);
}